// Round 5
// baseline (492.947 us; speedup 1.0000x reference)
//
#include <hip/hip_runtime.h>
#include <math.h>

#define NB 8
#define NCH 30
#define LL 16384
#define N1 6000
#define N2 4914
#define NCLS 5
#define KLIM 8192
#define ATT_K 13

typedef float f32x4 __attribute__((ext_vector_type(4)));

__device__ __forceinline__ unsigned fkey(float f) {
  unsigned u = __float_as_uint(f);
  unsigned m = (unsigned)(((int)u) >> 31) | 0x80000000u;
  return u ^ m;  // order-preserving float->uint
}
__device__ __forceinline__ float sigmoidf(float x) { return 1.f / (1.f + expf(-x)); }

// ---- K1: per-(b,c) mean pool over HxH = 16384 ----
__global__ void k_pool(const float* __restrict__ adj, float* __restrict__ pooled) {
  int bc = blockIdx.x;                       // 0..239
  const float* p = adj + (size_t)bc * LL;
  int tid = threadIdx.x;
  float s = 0.f;
  #pragma unroll
  for (int it = 0; it < LL / (256 * 4); ++it) {
    float4 v = *(const float4*)(p + it * 1024 + tid * 4);
    s += v.x + v.y + v.z + v.w;
  }
  #pragma unroll
  for (int m = 1; m < 64; m <<= 1) s += __shfl_xor(s, m);
  __shared__ float red[4];
  if ((tid & 63) == 0) red[tid >> 6] = s;
  __syncthreads();
  if (tid == 0) pooled[bc] = (red[0] + red[1] + red[2] + red[3]) * (1.f / (float)LL);
}

// ---- K2 (fused eca+wsum) ----
__global__ void k_wsum(const float* __restrict__ adj, const float* __restrict__ pooled,
                       const float* __restrict__ ew, float* __restrict__ y,
                       float* __restrict__ pmm, float* __restrict__ band_out) {
  int blk = blockIdx.x;                       // b*16 + tile
  int b = blk >> 4, tile = blk & 15;
  int tid = threadIdx.x;
  __shared__ float sc[NCH];
  if (tid < NCH) {
    int c = tid;
    const float* p = pooled + b * NCH;
    float s = ew[1] * p[c];
    if (c > 0)       s += ew[0] * p[c - 1];
    if (c < NCH - 1) s += ew[2] * p[c + 1];
    float scv = sigmoidf(s);
    sc[c] = scv;
    if (tile == 0) band_out[b * NCH + c] = scv;
  }
  __syncthreads();
  int j = tile * 1024 + tid * 4;
  const float* base = adj + (size_t)b * NCH * LL + j;
  float4 acc = {0.f, 0.f, 0.f, 0.f};
  #pragma unroll
  for (int c = 0; c < NCH; ++c) {
    float4 v = *(const float4*)(base + (size_t)c * LL);
    float s = sc[c];
    acc.x += v.x * s; acc.y += v.y * s; acc.z += v.z * s; acc.w += v.w * s;
  }
  *(float4*)(y + b * LL + j) = acc;
  float mn = fminf(fminf(acc.x, acc.y), fminf(acc.z, acc.w));
  float mx = fmaxf(fmaxf(acc.x, acc.y), fmaxf(acc.z, acc.w));
  #pragma unroll
  for (int m = 1; m < 64; m <<= 1) {
    mn = fminf(mn, __shfl_xor(mn, m));
    mx = fmaxf(mx, __shfl_xor(mx, m));
  }
  __shared__ float wmn[4], wmx[4];
  if ((tid & 63) == 0) { wmn[tid >> 6] = mn; wmx[tid >> 6] = mx; }
  __syncthreads();
  if (tid == 0) {
    mn = fminf(fminf(wmn[0], wmn[1]), fminf(wmn[2], wmn[3]));
    mx = fmaxf(fmaxf(wmx[0], wmx[1]), fmaxf(wmx[2], wmx[3]));
    pmm[blk * 2 + 0] = mn; pmm[blk * 2 + 1] = mx;
  }
}

// ---- K3 (fused): normalize -> conv13 -> exact top-8192 select -> scatter sparse ----
// Register diet: only kk[16] lives through the radix; s/v recomputed after select.
__global__ __launch_bounds__(1024) void k_selfuse(const float* __restrict__ y,
                                                  const float* __restrict__ pmm,
                                                  const float* __restrict__ w,
                                                  float* __restrict__ sp) {
  int b = blockIdx.x;
  int tid = threadIdx.x;
  int wave = tid >> 6, lane = tid & 63;
  extern __shared__ float vsh[];            // 16896 floats, idx(j) = j + (j>>5)
  __shared__ float wl[ATT_K];
  __shared__ int redw[16][3];
  __shared__ int ctot[3];
  __shared__ int wtot[16];
  if (tid < ATT_K) wl[tid] = w[tid];

  float mn = pmm[b * 32], mx = pmm[b * 32 + 1];
  #pragma unroll
  for (int t = 1; t < 16; ++t) {
    mn = fminf(mn, pmm[b * 32 + t * 2]);
    mx = fmaxf(mx, pmm[b * 32 + t * 2 + 1]);
  }
  float inv = 1.f / (mx - mn);

  const float* yb = y + b * LL;
  #pragma unroll
  for (int c = 0; c < 4; ++c) {
    int i = c * 4096 + tid * 4;
    float4 t4 = *(const float4*)(yb + i);
    int p0 = i + (i >> 5);
    vsh[p0 + 0] = (t4.x - mn) * inv;
    vsh[p0 + 1] = (t4.y - mn) * inv;
    vsh[p0 + 2] = (t4.z - mn) * inv;
    vsh[p0 + 3] = (t4.w - mn) * inv;
  }
  __syncthreads();

  int e = tid * 16;
  unsigned kk[16];
  {
    float v28[28];
    #pragma unroll
    for (int i = 0; i < 28; ++i) {
      int j = e - 6 + i;
      v28[i] = (j >= 0 && j < LL) ? vsh[j + (j >> 5)] : 0.f;
    }
    #pragma unroll
    for (int i = 0; i < 16; ++i) {
      float acc = 0.f;
      #pragma unroll
      for (int k = 0; k < ATT_K; ++k) acc += v28[i + k] * wl[k];
      kk[i] = fkey(acc);
    }
  }

  // 16 x 2-bit radix select; wave0 computes totals, 3-word broadcast
  unsigned p = 0; int need = KLIM;
  for (int pass = 0; pass < 16; ++pass) {
    int sh = 30 - pass * 2;
    unsigned himask = (pass == 0) ? 0u : (0xFFFFFFFFu << (sh + 2));
    int c3 = 0, c2 = 0, c1 = 0;
    #pragma unroll
    for (int i = 0; i < 16; ++i) {
      unsigned k2 = kk[i];
      if ((k2 & himask) == p) {
        unsigned bk = (k2 >> sh) & 3u;
        c3 += (bk == 3); c2 += (bk == 2); c1 += (bk == 1);
      }
    }
    #pragma unroll
    for (int m = 1; m < 64; m <<= 1) {
      c3 += __shfl_xor(c3, m); c2 += __shfl_xor(c2, m); c1 += __shfl_xor(c1, m);
    }
    if (lane == 0) { redw[wave][0] = c3; redw[wave][1] = c2; redw[wave][2] = c1; }
    __syncthreads();
    if (wave == 0) {
      int a0 = 0, a1 = 0, a2 = 0;
      if (lane < 16) { a0 = redw[lane][0]; a1 = redw[lane][1]; a2 = redw[lane][2]; }
      #pragma unroll
      for (int m = 1; m < 16; m <<= 1) {
        a0 += __shfl_xor(a0, m); a1 += __shfl_xor(a1, m); a2 += __shfl_xor(a2, m);
      }
      if (lane == 0) { ctot[0] = a0; ctot[1] = a1; ctot[2] = a2; }
    }
    __syncthreads();
    int C3 = ctot[0], C2 = ctot[1], C1 = ctot[2];
    if (C3 >= need)                { p |= 3u << sh; }
    else if (C3 + C2 >= need)      { p |= 2u << sh; need -= C3; }
    else if (C3 + C2 + C1 >= need) { p |= 1u << sh; need -= C3 + C2; }
    else                           { need -= C3 + C2 + C1; }
  }

  // rank equal keys in index order
  int cnt = 0;
  #pragma unroll
  for (int i = 0; i < 16; ++i) cnt += (kk[i] == p);
  int pre = cnt;
  #pragma unroll
  for (int m = 1; m < 64; m <<= 1) {
    int t = __shfl_up(pre, m);
    if (lane >= m) pre += t;
  }
  if (lane == 63) wtot[wave] = pre;
  __syncthreads();
  int base = 0;
  for (int t = 0; t < 16; ++t) if (t < wave) base += wtot[t];
  int rank = base + pre - cnt;

  // recompute conv + v, apply selection, vectorized store
  float v28[28];
  #pragma unroll
  for (int i = 0; i < 28; ++i) {
    int j = e - 6 + i;
    v28[i] = (j >= 0 && j < LL) ? vsh[j + (j >> 5)] : 0.f;
  }
  float outv[16];
  #pragma unroll
  for (int i = 0; i < 16; ++i) {
    float acc = 0.f;
    #pragma unroll
    for (int k = 0; k < ATT_K; ++k) acc += v28[i + k] * wl[k];
    bool sel;
    if (kk[i] > p) sel = true;
    else if (kk[i] == p) { sel = (rank < need); rank++; }
    else sel = false;
    outv[i] = sel ? v28[i + 6] * (sigmoidf(acc) + 1.f) : 0.f;
  }
  float* spb = sp + b * LL + e;
  #pragma unroll
  for (int q = 0; q < 4; ++q)
    *(f32x4*)(spb + q * 4) = *(f32x4*)(outv + q * 4);
}

// ---- K4: h = sp @ W1^T + b1 ; 128 threads, 2 waves, 4 rows/wave ----
__global__ __launch_bounds__(128) void k_gemm1(const float* __restrict__ W1, const float* __restrict__ b1,
                                               const float* __restrict__ sp, float* __restrict__ h) {
  int tid = threadIdx.x;
  int wave = tid >> 6, lane = tid & 63;
  int r0 = blockIdx.x * 8 + wave * 4;
  const float* wp = W1 + (size_t)r0 * LL;
  float acc[4][8];
  #pragma unroll
  for (int r = 0; r < 4; ++r)
    #pragma unroll
    for (int bb = 0; bb < 8; ++bb) acc[r][bb] = 0.f;
  for (int it = 0; it < 64; ++it) {
    int j = it * 256 + lane * 4;
    f32x4 wv[4];
    #pragma unroll
    for (int r = 0; r < 4; ++r)
      wv[r] = __builtin_nontemporal_load((const f32x4*)(wp + (size_t)r * LL + j));
    #pragma unroll
    for (int bb = 0; bb < 8; ++bb) {
      f32x4 s4 = *(const f32x4*)(sp + (size_t)bb * LL + j);
      #pragma unroll
      for (int r = 0; r < 4; ++r)
        acc[r][bb] += wv[r].x * s4.x + wv[r].y * s4.y + wv[r].z * s4.z + wv[r].w * s4.w;
    }
  }
  #pragma unroll
  for (int r = 0; r < 4; ++r)
    #pragma unroll
    for (int bb = 0; bb < 8; ++bb) {
      float a = acc[r][bb];
      #pragma unroll
      for (int m = 1; m < 64; m <<= 1) a += __shfl_xor(a, m);
      if (lane == 0) h[bb * N1 + r0 + r] = a + b1[r0 + r];
    }
}

// ---- K5: h2 = h @ W2^T + b2 ; 128 threads, 2 waves, 4 rows/wave, K=6000 ----
__global__ __launch_bounds__(128) void k_gemm2(const float* __restrict__ W2, const float* __restrict__ b2,
                                               const float* __restrict__ h, float* __restrict__ h2) {
  int tid = threadIdx.x;
  int wave = tid >> 6, lane = tid & 63;
  int r0 = blockIdx.x * 8 + wave * 4;
  const float* wp[4];
  #pragma unroll
  for (int r = 0; r < 4; ++r) {
    int row = r0 + r;
    wp[r] = W2 + (size_t)(row < N2 ? row : 0) * N1;
  }
  float acc[4][8];
  #pragma unroll
  for (int r = 0; r < 4; ++r)
    #pragma unroll
    for (int bb = 0; bb < 8; ++bb) acc[r][bb] = 0.f;
  for (int it = 0; it < 24; ++it) {
    int j = it * 256 + lane * 4;
    bool inb = j < N1;                       // N1 % 4 == 0
    f32x4 z = {0.f, 0.f, 0.f, 0.f};
    f32x4 wv[4];
    #pragma unroll
    for (int r = 0; r < 4; ++r)
      wv[r] = inb ? __builtin_nontemporal_load((const f32x4*)(wp[r] + j)) : z;
    #pragma unroll
    for (int bb = 0; bb < 8; ++bb) {
      f32x4 s4 = inb ? *(const f32x4*)(h + (size_t)bb * N1 + j) : z;
      #pragma unroll
      for (int r = 0; r < 4; ++r)
        acc[r][bb] += wv[r].x * s4.x + wv[r].y * s4.y + wv[r].z * s4.z + wv[r].w * s4.w;
    }
  }
  #pragma unroll
  for (int r = 0; r < 4; ++r)
    #pragma unroll
    for (int bb = 0; bb < 8; ++bb) {
      float a = acc[r][bb];
      #pragma unroll
      for (int m = 1; m < 64; m <<= 1) a += __shfl_xor(a, m);
      int row = r0 + r;
      if (lane == 0 && row < N2) h2[bb * N2 + row] = a + b2[row];
    }
}

// ---- K6 (fused cls1+final): t = h2@Wc1^T ; logits = t@Wc2^T ; log_softmax ----
__global__ void k_tail(const float* __restrict__ h2, const float* __restrict__ Wc1,
                       const float* __restrict__ Wc2, float* __restrict__ out) {
  int b = blockIdx.x;
  int tid = threadIdx.x;
  int wave = tid >> 6, lane = tid & 63;
  __shared__ float tt[32];
  const float* hb = h2 + b * N2;
  for (int m = wave; m < 32; m += 4) {
    const float* wm = Wc1 + m * N2;
    float s = 0.f;
    for (int j = lane; j < N2; j += 64) s += hb[j] * wm[j];
    #pragma unroll
    for (int mm = 1; mm < 64; mm <<= 1) s += __shfl_xor(s, mm);
    if (lane == 0) tt[m] = s;
  }
  __syncthreads();
  if (tid == 0) {
    float lg[NCLS];
    #pragma unroll
    for (int k = 0; k < NCLS; ++k) {
      float s = 0.f;
      #pragma unroll
      for (int m = 0; m < 32; ++m) s += tt[m] * Wc2[k * 32 + m];
      lg[k] = s;
    }
    float mx = lg[0];
    #pragma unroll
    for (int k = 1; k < NCLS; ++k) mx = fmaxf(mx, lg[k]);
    float se = 0.f;
    #pragma unroll
    for (int k = 0; k < NCLS; ++k) se += expf(lg[k] - mx);
    float lse = logf(se);
    #pragma unroll
    for (int k = 0; k < NCLS; ++k) out[b * NCLS + k] = lg[k] - mx - lse;
  }
}

extern "C" void kernel_launch(void* const* d_in, const int* in_sizes, int n_in,
                              void* d_out, int out_size, void* d_ws, size_t ws_size,
                              hipStream_t stream) {
  const float* adj   = (const float*)d_in[0];
  const float* eca_w = (const float*)d_in[1];
  const float* att_w = (const float*)d_in[2];
  const float* W1    = (const float*)d_in[3];
  const float* b1    = (const float*)d_in[4];
  const float* W2    = (const float*)d_in[5];
  const float* b2    = (const float*)d_in[6];
  const float* Wc1   = (const float*)d_in[7];
  const float* Wc2   = (const float*)d_in[8];
  float* out = (float*)d_out;
  float* ws  = (float*)d_ws;

  float* pooled = ws;              // 240
  float* pmm    = ws + 512;        // 256
  float* y      = ws + 1024;       // 131072
  float* sp     = y  + NB * LL;    // 131072
  float* h      = sp + NB * LL;    // 48000
  float* h2     = h  + NB * N1;    // 39312

  k_pool   <<<NB * NCH, 256, 0, stream>>>(adj, pooled);
  k_wsum   <<<NB * 16, 256, 0, stream>>>(adj, pooled, eca_w, y, pmm, out + NB * NCLS);
  k_selfuse<<<NB, 1024, 16896 * sizeof(float), stream>>>(y, pmm, att_w, sp);
  k_gemm1  <<<N1 / 8, 128, 0, stream>>>(W1, b1, sp, h);
  k_gemm2  <<<(N2 + 7) / 8, 128, 0, stream>>>(W2, b2, h, h2);
  k_tail   <<<NB, 256, 0, stream>>>(h2, Wc1, Wc2, out);
}

// Round 6
// 390.854 us; speedup vs baseline: 1.2612x; 1.2612x over previous
//
#include <hip/hip_runtime.h>
#include <hip/hip_cooperative_groups.h>
#include <math.h>

namespace cg = cooperative_groups;

#define NB 8
#define NCH 30
#define LL 16384
#define N1 6000
#define N2 4914
#define NCLS 5
#define KLIM 8192
#define ATT_K 13

typedef float f32x4 __attribute__((ext_vector_type(4)));

__device__ __forceinline__ unsigned fkey(float f) {
  unsigned u = __float_as_uint(f);
  unsigned m = (unsigned)(((int)u) >> 31) | 0x80000000u;
  return u ^ m;  // order-preserving float->uint
}
__device__ __forceinline__ float sigmoidf(float x) { return 1.f / (1.f + expf(-x)); }

// One cooperative kernel, 256 blocks x 1024 threads, 1 block/CU.
// Phases separated by grid.sync(); no inter-kernel gaps, one rocprof row.
__global__ __launch_bounds__(1024, 4) void k_mega(
    const float* __restrict__ adj, const float* __restrict__ eca_w,
    const float* __restrict__ att_w,
    const float* __restrict__ W1, const float* __restrict__ b1,
    const float* __restrict__ W2, const float* __restrict__ b2,
    const float* __restrict__ Wc1, const float* __restrict__ Wc2,
    float* __restrict__ out,
    float* __restrict__ pooled, float* __restrict__ pmm,
    float* __restrict__ y, float* __restrict__ sp,
    float* __restrict__ h, float* __restrict__ h2, float* __restrict__ tbuf) {
  cg::grid_group grid = cg::this_grid();
  extern __shared__ float vsh[];            // 16896 floats, idx(j) = j + (j>>5)
  int bid = blockIdx.x;
  int tid = threadIdx.x;
  int wave = tid >> 6, lane = tid & 63;

  __shared__ float red16[16];

  // ---------- P1: pool (blocks 0..239 = one (b,c) each) ----------
  if (bid < NB * NCH) {
    const float* p = adj + (size_t)bid * LL;
    float s = 0.f;
    #pragma unroll
    for (int c = 0; c < 4; ++c) {
      float4 v = *(const float4*)(p + c * 4096 + tid * 4);
      s += v.x + v.y + v.z + v.w;
    }
    #pragma unroll
    for (int m = 1; m < 64; m <<= 1) s += __shfl_xor(s, m);
    if (lane == 0) red16[wave] = s;
    __syncthreads();
    if (tid == 0) {
      float t = 0.f;
      #pragma unroll
      for (int q = 0; q < 16; ++q) t += red16[q];
      pooled[bid] = t * (1.f / (float)LL);
    }
  }
  grid.sync();

  // ---------- P2: eca + weighted sum + partial minmax (blocks 0..127) ----------
  if (bid < 128) {
    int b = bid >> 4, tile = bid & 15;
    __shared__ float sc[NCH];
    __shared__ float wmn[16], wmx[16];
    if (tid < NCH) {
      int c = tid;
      const float* p = pooled + b * NCH;
      float s = eca_w[1] * p[c];
      if (c > 0)       s += eca_w[0] * p[c - 1];
      if (c < NCH - 1) s += eca_w[2] * p[c + 1];
      float scv = sigmoidf(s);
      sc[c] = scv;
      if (tile == 0) out[NB * NCLS + b * NCH + c] = scv;   // band_score
    }
    __syncthreads();
    int j = tile * 1024 + tid;
    const float* base = adj + (size_t)b * NCH * LL + j;
    float acc = 0.f;
    #pragma unroll
    for (int c = 0; c < NCH; ++c) acc += base[(size_t)c * LL] * sc[c];
    y[b * LL + j] = acc;
    float mn = acc, mx = acc;
    #pragma unroll
    for (int m = 1; m < 64; m <<= 1) {
      mn = fminf(mn, __shfl_xor(mn, m));
      mx = fmaxf(mx, __shfl_xor(mx, m));
    }
    if (lane == 0) { wmn[wave] = mn; wmx[wave] = mx; }
    __syncthreads();
    if (tid == 0) {
      #pragma unroll
      for (int q = 1; q < 16; ++q) {
        wmn[0] = fminf(wmn[0], wmn[q]);
        wmx[0] = fmaxf(wmx[0], wmx[q]);
      }
      pmm[bid * 2 + 0] = wmn[0]; pmm[bid * 2 + 1] = wmx[0];
    }
  }
  grid.sync();

  // ---------- P3: normalize -> conv13 -> top-8192 radix select -> sparse (blocks 0..7) ----------
  if (bid < NB) {
    int b = bid;
    __shared__ float wl[ATT_K];
    __shared__ int redw[16][3];
    __shared__ int ctot[3];
    __shared__ int wtot[16];
    if (tid < ATT_K) wl[tid] = att_w[tid];

    float mn = pmm[b * 32], mx = pmm[b * 32 + 1];
    #pragma unroll
    for (int t = 1; t < 16; ++t) {
      mn = fminf(mn, pmm[b * 32 + t * 2]);
      mx = fmaxf(mx, pmm[b * 32 + t * 2 + 1]);
    }
    float inv = 1.f / (mx - mn);

    const float* yb = y + b * LL;
    #pragma unroll
    for (int c = 0; c < 4; ++c) {
      int i = c * 4096 + tid * 4;
      float4 t4 = *(const float4*)(yb + i);
      int p0 = i + (i >> 5);
      vsh[p0 + 0] = (t4.x - mn) * inv;
      vsh[p0 + 1] = (t4.y - mn) * inv;
      vsh[p0 + 2] = (t4.z - mn) * inv;
      vsh[p0 + 3] = (t4.w - mn) * inv;
    }
    __syncthreads();

    int e = tid * 16;
    unsigned kk[16];
    {
      float v28[28];
      #pragma unroll
      for (int i = 0; i < 28; ++i) {
        int j = e - 6 + i;
        v28[i] = (j >= 0 && j < LL) ? vsh[j + (j >> 5)] : 0.f;
      }
      #pragma unroll
      for (int i = 0; i < 16; ++i) {
        float acc = 0.f;
        #pragma unroll
        for (int k = 0; k < ATT_K; ++k) acc += v28[i + k] * wl[k];
        kk[i] = fkey(acc);
      }
    }

    unsigned p = 0; int need = KLIM;
    for (int pass = 0; pass < 16; ++pass) {
      int sh = 30 - pass * 2;
      unsigned himask = (pass == 0) ? 0u : (0xFFFFFFFFu << (sh + 2));
      int c3 = 0, c2 = 0, c1 = 0;
      #pragma unroll
      for (int i = 0; i < 16; ++i) {
        unsigned k2 = kk[i];
        if ((k2 & himask) == p) {
          unsigned bk = (k2 >> sh) & 3u;
          c3 += (bk == 3); c2 += (bk == 2); c1 += (bk == 1);
        }
      }
      #pragma unroll
      for (int m = 1; m < 64; m <<= 1) {
        c3 += __shfl_xor(c3, m); c2 += __shfl_xor(c2, m); c1 += __shfl_xor(c1, m);
      }
      if (lane == 0) { redw[wave][0] = c3; redw[wave][1] = c2; redw[wave][2] = c1; }
      __syncthreads();
      if (wave == 0) {
        int a0 = 0, a1 = 0, a2 = 0;
        if (lane < 16) { a0 = redw[lane][0]; a1 = redw[lane][1]; a2 = redw[lane][2]; }
        #pragma unroll
        for (int m = 1; m < 16; m <<= 1) {
          a0 += __shfl_xor(a0, m); a1 += __shfl_xor(a1, m); a2 += __shfl_xor(a2, m);
        }
        if (lane == 0) { ctot[0] = a0; ctot[1] = a1; ctot[2] = a2; }
      }
      __syncthreads();
      int C3 = ctot[0], C2 = ctot[1], C1 = ctot[2];
      if (C3 >= need)                { p |= 3u << sh; }
      else if (C3 + C2 >= need)      { p |= 2u << sh; need -= C3; }
      else if (C3 + C2 + C1 >= need) { p |= 1u << sh; need -= C3 + C2; }
      else                           { need -= C3 + C2 + C1; }
    }

    int cnt = 0;
    #pragma unroll
    for (int i = 0; i < 16; ++i) cnt += (kk[i] == p);
    int pre = cnt;
    #pragma unroll
    for (int m = 1; m < 64; m <<= 1) {
      int t = __shfl_up(pre, m);
      if (lane >= m) pre += t;
    }
    if (lane == 63) wtot[wave] = pre;
    __syncthreads();
    int base = 0;
    for (int t = 0; t < 16; ++t) if (t < wave) base += wtot[t];
    int rank = base + pre - cnt;

    float v28[28];
    #pragma unroll
    for (int i = 0; i < 28; ++i) {
      int j = e - 6 + i;
      v28[i] = (j >= 0 && j < LL) ? vsh[j + (j >> 5)] : 0.f;
    }
    float outv[16];
    #pragma unroll
    for (int i = 0; i < 16; ++i) {
      float acc = 0.f;
      #pragma unroll
      for (int k = 0; k < ATT_K; ++k) acc += v28[i + k] * wl[k];
      bool sel;
      if (kk[i] > p) sel = true;
      else if (kk[i] == p) { sel = (rank < need); rank++; }
      else sel = false;
      outv[i] = sel ? v28[i + 6] * (sigmoidf(acc) + 1.f) : 0.f;
    }
    float* spb = sp + b * LL + e;
    #pragma unroll
    for (int q = 0; q < 4; ++q)
      *(f32x4*)(spb + q * 4) = *(f32x4*)(outv + q * 4);
  }
  grid.sync();

  // ---------- P4: h = sp @ W1^T + b1 ; pair = wave*256+bid so all CUs stream ----------
  {
    int pair = wave * 256 + bid;            // 0..4095
    int r0 = pair * 2;
    if (r0 < N1) {                          // r0+1 <= 5999
      const float* w0p = W1 + (size_t)r0 * LL;
      const float* w1p = w0p + LL;
      float acc0[8], acc1[8];
      #pragma unroll
      for (int bb = 0; bb < 8; ++bb) { acc0[bb] = 0.f; acc1[bb] = 0.f; }
      #pragma unroll 2
      for (int it = 0; it < 64; ++it) {
        int j = it * 256 + lane * 4;
        f32x4 w0 = __builtin_nontemporal_load((const f32x4*)(w0p + j));
        f32x4 w1 = __builtin_nontemporal_load((const f32x4*)(w1p + j));
        #pragma unroll
        for (int bb = 0; bb < 8; ++bb) {
          f32x4 s4 = *(const f32x4*)(sp + (size_t)bb * LL + j);
          acc0[bb] += w0.x * s4.x + w0.y * s4.y + w0.z * s4.z + w0.w * s4.w;
          acc1[bb] += w1.x * s4.x + w1.y * s4.y + w1.z * s4.z + w1.w * s4.w;
        }
      }
      #pragma unroll
      for (int bb = 0; bb < 8; ++bb) {
        float a0 = acc0[bb], a1 = acc1[bb];
        #pragma unroll
        for (int m = 1; m < 64; m <<= 1) {
          a0 += __shfl_xor(a0, m);
          a1 += __shfl_xor(a1, m);
        }
        if (lane == 0) {
          h[bb * N1 + r0]     = a0 + b1[r0];
          h[bb * N1 + r0 + 1] = a1 + b1[r0 + 1];
        }
      }
    }
  }
  grid.sync();

  // ---------- P5: h2 = h @ W2^T + b2 ----------
  {
    int pair = wave * 256 + bid;            // 0..4095
    int r0 = pair * 2;
    if (r0 < N2) {                          // N2 even -> r0+1 <= 4913
      const float* w0p = W2 + (size_t)r0 * N1;
      const float* w1p = w0p + N1;
      float acc0[8], acc1[8];
      #pragma unroll
      for (int bb = 0; bb < 8; ++bb) { acc0[bb] = 0.f; acc1[bb] = 0.f; }
      #pragma unroll 2
      for (int it = 0; it < 24; ++it) {
        int j = it * 256 + lane * 4;
        bool inb = j < N1;                  // N1 % 4 == 0
        f32x4 z = {0.f, 0.f, 0.f, 0.f};
        f32x4 w0 = z, w1 = z;
        if (inb) {
          w0 = __builtin_nontemporal_load((const f32x4*)(w0p + j));
          w1 = __builtin_nontemporal_load((const f32x4*)(w1p + j));
        }
        #pragma unroll
        for (int bb = 0; bb < 8; ++bb) {
          f32x4 s4 = inb ? *(const f32x4*)(h + (size_t)bb * N1 + j) : z;
          acc0[bb] += w0.x * s4.x + w0.y * s4.y + w0.z * s4.z + w0.w * s4.w;
          acc1[bb] += w1.x * s4.x + w1.y * s4.y + w1.z * s4.z + w1.w * s4.w;
        }
      }
      #pragma unroll
      for (int bb = 0; bb < 8; ++bb) {
        float a0 = acc0[bb], a1 = acc1[bb];
        #pragma unroll
        for (int m = 1; m < 64; m <<= 1) {
          a0 += __shfl_xor(a0, m);
          a1 += __shfl_xor(a1, m);
        }
        if (lane == 0) {
          h2[bb * N2 + r0]     = a0 + b2[r0];
          h2[bb * N2 + r0 + 1] = a1 + b2[r0 + 1];
        }
      }
    }
  }
  grid.sync();

  // ---------- P6: t[b,m] = h2[b,:] . Wc1[m,:] (256 blocks = one (b,m) each) ----------
  {
    int b = bid >> 5, m = bid & 31;
    const float* hb = h2 + b * N2;
    const float* wm = Wc1 + m * N2;
    float s = 0.f;
    for (int j = tid; j < N2; j += 1024) s += hb[j] * wm[j];
    #pragma unroll
    for (int mm = 1; mm < 64; mm <<= 1) s += __shfl_xor(s, mm);
    __shared__ float redc[16];
    if (lane == 0) redc[wave] = s;
    __syncthreads();
    if (tid == 0) {
      float t = 0.f;
      #pragma unroll
      for (int q = 0; q < 16; ++q) t += redc[q];
      tbuf[bid] = t;
    }
  }
  grid.sync();

  // ---------- P7: logits + log_softmax (blocks 0..7, thread 0) ----------
  if (bid < NB && tid == 0) {
    int b = bid;
    float lg[NCLS];
    #pragma unroll
    for (int k = 0; k < NCLS; ++k) {
      float s = 0.f;
      #pragma unroll
      for (int m = 0; m < 32; ++m) s += tbuf[b * 32 + m] * Wc2[k * 32 + m];
      lg[k] = s;
    }
    float mx = lg[0];
    #pragma unroll
    for (int k = 1; k < NCLS; ++k) mx = fmaxf(mx, lg[k]);
    float se = 0.f;
    #pragma unroll
    for (int k = 0; k < NCLS; ++k) se += expf(lg[k] - mx);
    float lse = logf(se);
    #pragma unroll
    for (int k = 0; k < NCLS; ++k) out[b * NCLS + k] = lg[k] - mx - lse;
  }
}

extern "C" void kernel_launch(void* const* d_in, const int* in_sizes, int n_in,
                              void* d_out, int out_size, void* d_ws, size_t ws_size,
                              hipStream_t stream) {
  const float* adj   = (const float*)d_in[0];
  const float* eca_w = (const float*)d_in[1];
  const float* att_w = (const float*)d_in[2];
  const float* W1    = (const float*)d_in[3];
  const float* b1    = (const float*)d_in[4];
  const float* W2    = (const float*)d_in[5];
  const float* b2    = (const float*)d_in[6];
  const float* Wc1   = (const float*)d_in[7];
  const float* Wc2   = (const float*)d_in[8];
  float* out = (float*)d_out;
  float* ws  = (float*)d_ws;

  float* pooled = ws;              // 240
  float* pmm    = ws + 512;        // 256
  float* tbuf   = ws + 768;        // 256
  float* y      = ws + 1024;       // 131072
  float* sp     = y  + NB * LL;    // 131072
  float* h      = sp + NB * LL;    // 48000
  float* h2     = h  + NB * N1;    // 39312

  void* args[] = {
    (void*)&adj, (void*)&eca_w, (void*)&att_w,
    (void*)&W1, (void*)&b1, (void*)&W2, (void*)&b2,
    (void*)&Wc1, (void*)&Wc2, (void*)&out,
    (void*)&pooled, (void*)&pmm, (void*)&y, (void*)&sp,
    (void*)&h, (void*)&h2, (void*)&tbuf,
  };
  hipLaunchCooperativeKernel((void*)k_mega, dim3(256), dim3(1024),
                             args, 16896 * sizeof(float), stream);
}